// Round 1
// baseline (815.629 us; speedup 1.0000x reference)
//
#include <hip/hip_runtime.h>

typedef unsigned short u16;
typedef __attribute__((ext_vector_type(8))) short short8;
typedef __attribute__((ext_vector_type(4))) float floatx4;

// ---------- bf16 helpers (manual, bit-exact enough; RNE) ----------
__device__ __forceinline__ float bf2f(u16 u) {
    return __uint_as_float(((unsigned int)u) << 16);
}
__device__ __forceinline__ u16 f2bf(float f) {
    unsigned int i = __float_as_uint(f);
    unsigned int r = i + 0x7FFFu + ((i >> 16) & 1u);
    return (u16)(r >> 16);
}

// ---------- async global->LDS (16B per lane, wave-uniform LDS base) ----------
typedef __attribute__((address_space(3))) void lds_void;
typedef const __attribute__((address_space(1))) void g_void;
__device__ __forceinline__ void async_copy16(const void* g, void* l) {
    __builtin_amdgcn_global_load_lds((g_void*)g, (lds_void*)l, 16, 0, 0);
}

// ================= problem constants =================
#define E_BONDS 131072
#define N_ATOMS_C 65536
#define HID 256
#define KPAD_I 160     // 157 padded
#define KPAD_O 416     // 399 padded
#define N_MOLS 2048

// ================= prep kernels =================
// fbonds [E,157] f32 -> [E,160] bf16 (pad 0)
__global__ __launch_bounds__(256) void prep_fbonds(const float* __restrict__ fb, u16* __restrict__ out) {
    int idx = blockIdx.x * 256 + threadIdx.x;           // E*160 total
    int row = idx / KPAD_I;
    int col = idx - row * KPAD_I;
    float v = (col < 157) ? fb[(size_t)row * 157 + col] : 0.f;
    out[idx] = f2bf(v);
}

// W [K,256] f32 -> Wt [256, Kpad] bf16 (transposed, zero-padded)
__global__ __launch_bounds__(256) void prep_wt(const float* __restrict__ W, u16* __restrict__ Wt, int K, int Kpad) {
    int idx = blockIdx.x * 256 + threadIdx.x;           // 256*Kpad total
    int n = idx / Kpad;
    int k = idx - n * Kpad;
    float v = (k < K) ? W[(size_t)k * 256 + n] : 0.f;
    Wt[idx] = f2bf(v);
}

// W_o_w [399,256] -> reordered transposed [256,416]: k<256 -> W[143+k][n]; k<399 -> W[k-256][n]; else 0
__global__ __launch_bounds__(256) void prep_wo(const float* __restrict__ W, u16* __restrict__ Wt) {
    int idx = blockIdx.x * 256 + threadIdx.x;           // 256*416 total
    int n = idx / KPAD_O;
    int k = idx - n * KPAD_O;
    float v = 0.f;
    if (k < 256)      v = W[(size_t)(143 + k) * 256 + n];
    else if (k < 399) v = W[(size_t)(k - 256) * 256 + n];
    Wt[idx] = f2bf(v);
}

// ================= MFMA GEMM: C[M,256] = epi(A[M,K] @ Bt[256,K]^T) =================
// EPI: 0 plain->out ; 1 write out2=pre, out=relu(pre) ; 2 out=relu(src+acc) ; 3 out=relu(acc+bias)
template <int EPI>
__global__ __launch_bounds__(256) void gemm_bt(
    const u16* __restrict__ A, const u16* __restrict__ Bt,
    u16* __restrict__ out, u16* __restrict__ out2,
    const u16* __restrict__ src, const float* __restrict__ bias,
    int K)
{
    __shared__ u16 Al[4096];   // [kb=4][row=128][8]
    __shared__ u16 Bl[4096];

    const int tid = threadIdx.x;
    const int wave = tid >> 6, lane = tid & 63;
    const int wm = wave >> 1, wn = wave & 1;
    const int m0 = blockIdx.x * 128;
    const int n0 = blockIdx.y * 128;
    const int quad = lane >> 4, mr = lane & 15;

    floatx4 acc[4][4] = {};

    // staging: chunk c = tid (issue1) and tid+256 (issue2); kb=c>>7, row=c&127
    const u16* Ag = A  + (size_t)(m0 + (tid & 127)) * K + ((tid >> 7) << 3);
    const u16* Bg = Bt + (size_t)(n0 + (tid & 127)) * K + ((tid >> 7) << 3);
    u16* al1 = Al + wave * 512;          // bytes: wave*1024
    u16* al2 = Al + 2048 + wave * 512;
    u16* bl1 = Bl + wave * 512;
    u16* bl2 = Bl + 2048 + wave * 512;

    for (int k0 = 0; k0 < K; k0 += 32) {
        async_copy16(Ag + k0,      al1);
        async_copy16(Ag + k0 + 16, al2);
        async_copy16(Bg + k0,      bl1);
        async_copy16(Bg + k0 + 16, bl2);
        __syncthreads();

        short8 af[4], bfv[4];
#pragma unroll
        for (int i = 0; i < 4; ++i)
            af[i] = *(const short8*)(Al + quad * 1024 + (wm * 64 + i * 16 + mr) * 8);
#pragma unroll
        for (int j = 0; j < 4; ++j)
            bfv[j] = *(const short8*)(Bl + quad * 1024 + (wn * 64 + j * 16 + mr) * 8);
#pragma unroll
        for (int i = 0; i < 4; ++i)
#pragma unroll
            for (int j = 0; j < 4; ++j)
                acc[i][j] = __builtin_amdgcn_mfma_f32_16x16x32_bf16(af[i], bfv[j], acc[i][j], 0, 0, 0);
        __syncthreads();
    }

    // epilogue: D row=(lane>>4)*4+r, col=lane&15 (HW-verified)
#pragma unroll
    for (int i = 0; i < 4; ++i) {
        int row0 = m0 + wm * 64 + i * 16 + ((lane >> 4) << 2);
#pragma unroll
        for (int j = 0; j < 4; ++j) {
            int col = n0 + wn * 64 + j * 16 + (lane & 15);
#pragma unroll
            for (int r = 0; r < 4; ++r) {
                size_t off = (size_t)(row0 + r) * 256 + col;
                float v = acc[i][j][r];
                if (EPI == 0) {
                    out[off] = f2bf(v);
                } else if (EPI == 1) {
                    out2[off] = f2bf(v);
                    out[off] = f2bf(v > 0.f ? v : 0.f);
                } else if (EPI == 2) {
                    v += bf2f(src[off]);
                    out[off] = f2bf(v > 0.f ? v : 0.f);
                } else {
                    v += bias[col];
                    out[off] = f2bf(v > 0.f ? v : 0.f);
                }
            }
        }
    }
}

// ================= bond gather + neighbor softmax-attention =================
// one wave per bond: nei[e] = sum_j softmax_j(msg_j . W_ma1) * msg_j
__global__ __launch_bounds__(256) void bond_attn(const u16* __restrict__ message, const int* __restrict__ bgraph,
                                                 const float* __restrict__ Wma, u16* __restrict__ nei) {
    int wave = threadIdx.x >> 6, lane = threadIdx.x & 63;
    int e = blockIdx.x * 4 + wave;
    const float4 w = *(const float4*)(Wma + lane * 4);
    const int* bg = bgraph + (size_t)e * 6;
    float mj[6][4];
    float s[6];
#pragma unroll
    for (int j = 0; j < 6; ++j) {
        int b = bg[j];
        ushort4 u = *(const ushort4*)(message + (size_t)b * 256 + lane * 4);
        mj[j][0] = bf2f(u.x); mj[j][1] = bf2f(u.y); mj[j][2] = bf2f(u.z); mj[j][3] = bf2f(u.w);
        float p = mj[j][0] * w.x + mj[j][1] * w.y + mj[j][2] * w.z + mj[j][3] * w.w;
#pragma unroll
        for (int off = 32; off > 0; off >>= 1) p += __shfl_xor(p, off);
        s[j] = p;
    }
    float mx = fmaxf(fmaxf(fmaxf(s[0], s[1]), fmaxf(s[2], s[3])), fmaxf(s[4], s[5]));
    float ex[6]; float den = 0.f;
#pragma unroll
    for (int j = 0; j < 6; ++j) { ex[j] = __expf(s[j] - mx); den += ex[j]; }
    float inv = 1.f / den;
    float o0 = 0, o1 = 0, o2 = 0, o3 = 0;
#pragma unroll
    for (int j = 0; j < 6; ++j) {
        float wj = ex[j] * inv;
        o0 += wj * mj[j][0]; o1 += wj * mj[j][1]; o2 += wj * mj[j][2]; o3 += wj * mj[j][3];
    }
    ushort4 o; o.x = f2bf(o0); o.y = f2bf(o1); o.z = f2bf(o2); o.w = f2bf(o3);
    *(ushort4*)(nei + (size_t)e * 256 + lane * 4) = o;
}

// ================= atom aggregation -> ainput [N,416] = [nei_a(256) | fatoms(143) | 0(17)] =================
__global__ __launch_bounds__(256) void atom_agg(const u16* __restrict__ message, const int* __restrict__ agraph,
                                                const float* __restrict__ fatoms, u16* __restrict__ ainput) {
    int wave = threadIdx.x >> 6, lane = threadIdx.x & 63;
    int a = blockIdx.x * 4 + wave;
    const int* ag = agraph + (size_t)a * 6;
    float a0 = 0, a1 = 0, a2 = 0, a3 = 0;
#pragma unroll
    for (int j = 0; j < 6; ++j) {
        int b = ag[j];
        ushort4 u = *(const ushort4*)(message + (size_t)b * 256 + lane * 4);
        a0 += bf2f(u.x); a1 += bf2f(u.y); a2 += bf2f(u.z); a3 += bf2f(u.w);
    }
    u16* arow = ainput + (size_t)a * KPAD_O;
    ushort4 o; o.x = f2bf(a0); o.y = f2bf(a1); o.z = f2bf(a2); o.w = f2bf(a3);
    *(ushort4*)(arow + lane * 4) = o;
    const float* frow = fatoms + (size_t)a * 143;
    for (int c = lane; c < 143; c += 64) arow[256 + c] = f2bf(frow[c]);
    if (lane < 17) arow[399 + lane] = 0;
}

// ================= per-molecule self-attention: z = softmax(hW @ h^T) @ h =================
#define HSTR 260
__global__ __launch_bounds__(256) void mol_attn(const u16* __restrict__ atomh, const u16* __restrict__ hWg,
                                                u16* __restrict__ z) {
    __shared__ float hs[32 * HSTR];
    __shared__ float P[32 * 33];
    const int t = threadIdx.x;
    const int b = blockIdx.x;
    const u16* hbase = atomh + (size_t)b * 32 * 256;
    for (int e0 = t * 4; e0 < 8192; e0 += 1024) {
        int row = e0 >> 8, col = e0 & 255;
        ushort4 u = *(const ushort4*)(hbase + e0);
        floatx4 v; v.x = bf2f(u.x); v.y = bf2f(u.y); v.z = bf2f(u.z); v.w = bf2f(u.w);
        *(floatx4*)&hs[row * HSTR + col] = v;
    }
    __syncthreads();

    // scores: thread (c = t&31, a = t>>5 + 8r)
    {
        int c = t & 31, a0 = t >> 5;
        const u16* hWb = hWg + (size_t)b * 32 * 256;
        for (int r = 0; r < 4; ++r) {
            int a = a0 + r * 8;
            const u16* hwrow = hWb + a * 256;
            float s = 0.f;
            for (int d = 0; d < 256; d += 4) {
                ushort4 u = *(const ushort4*)(hwrow + d);
                const float* hp = &hs[c * HSTR + d];
                s += bf2f(u.x) * hp[0] + bf2f(u.y) * hp[1] + bf2f(u.z) * hp[2] + bf2f(u.w) * hp[3];
            }
            P[a * 33 + c] = s;
        }
    }
    __syncthreads();
    if (t < 32) {
        float* prow = &P[t * 33];
        float mx = prow[0];
        for (int i = 1; i < 32; ++i) mx = fmaxf(mx, prow[i]);
        float den = 0.f;
        for (int i = 0; i < 32; ++i) { float ev = __expf(prow[i] - mx); prow[i] = ev; den += ev; }
        float inv = 1.f / den;
        for (int i = 0; i < 32; ++i) prow[i] *= inv;
    }
    __syncthreads();

    // z: thread (a = t>>3, q = t&7) covers cols q*4 + 32i
    {
        int a = t >> 3, q = t & 7;
        floatx4 acc8[8];
#pragma unroll
        for (int i = 0; i < 8; ++i) acc8[i] = (floatx4){0.f, 0.f, 0.f, 0.f};
        const float* prow = &P[a * 33];
        for (int cc = 0; cc < 32; ++cc) {
            float p = prow[cc];
            const float* hrow = &hs[cc * HSTR + q * 4];
#pragma unroll
            for (int i = 0; i < 8; ++i) {
                floatx4 hv = *(const floatx4*)(hrow + i * 32);
                acc8[i] += p * hv;
            }
        }
        u16* zrow = z + ((size_t)b * 32 + a) * 256 + q * 4;
#pragma unroll
        for (int i = 0; i < 8; ++i) {
            ushort4 o;
            o.x = f2bf(acc8[i].x); o.y = f2bf(acc8[i].y); o.z = f2bf(acc8[i].z); o.w = f2bf(acc8[i].w);
            *(ushort4*)(zrow + i * 32) = o;
        }
    }
}

// ================= final: out[b,d] = sum_a (h + att_h) / 32 =================
__global__ __launch_bounds__(256) void final_reduce(const u16* __restrict__ atomh, const u16* __restrict__ atth,
                                                    float* __restrict__ out) {
    int idx = blockIdx.x * 256 + threadIdx.x;   // 2048*256
    int b = idx >> 8, d = idx & 255;
    const u16* ph = atomh + ((size_t)b * 32) * 256 + d;
    const u16* pa = atth + ((size_t)b * 32) * 256 + d;
    float s = 0.f;
#pragma unroll 4
    for (int a = 0; a < 32; ++a) s += bf2f(ph[a * 256]) + bf2f(pa[a * 256]);
    out[idx] = s * 0.03125f;
}

// ================= workspace layout (bytes) =================
#define O_FBP      ((size_t)0)                        // 41,943,040   E*160*2   -> later atom_h
#define O_BINPUT   ((size_t)41943040)                 // 67,108,864   E*256*2   -> later hW (+0), z (+33554432)
#define O_MESSAGE  ((size_t)109051904)                // 67,108,864   E*256*2   -> later att_h
#define O_NEI      ((size_t)176160768)                // 67,108,864   E*256*2   -> later ainput
#define O_W        ((size_t)243269632)
#define O_WTI      (O_W)                              // 256*160*2 = 81,920
#define O_WTH      (O_W + 81920)                      // 131,072
#define O_WTO      (O_W + 212992)                     // 256*416*2 = 212,992
#define O_WTA      (O_W + 425984)                     // 131,072
#define O_WTB      (O_W + 557056)                     // 131,072
#define WS_NEED    ((size_t)243957760)

extern "C" void kernel_launch(void* const* d_in, const int* in_sizes, int n_in,
                              void* d_out, int out_size, void* d_ws, size_t ws_size,
                              hipStream_t stream) {
    const float* fatoms = (const float*)d_in[0];
    const float* fbonds = (const float*)d_in[1];
    const int*   agraph = (const int*)d_in[2];
    const int*   bgraph = (const int*)d_in[3];
    const float* W_i    = (const float*)d_in[5];
    const float* W_h    = (const float*)d_in[6];
    const float* W_o_w  = (const float*)d_in[7];
    const float* W_o_b  = (const float*)d_in[8];
    const float* W_a    = (const float*)d_in[9];
    const float* W_b_w  = (const float*)d_in[10];
    const float* W_b_b  = (const float*)d_in[11];
    const float* W_ma1  = (const float*)d_in[12];
    float* out = (float*)d_out;

    if (ws_size < WS_NEED) return;  // visible failure rather than corruption

    char* ws = (char*)d_ws;
    u16* fbp     = (u16*)(ws + O_FBP);
    u16* binput  = (u16*)(ws + O_BINPUT);
    u16* message = (u16*)(ws + O_MESSAGE);
    u16* nei     = (u16*)(ws + O_NEI);
    u16* wti     = (u16*)(ws + O_WTI);
    u16* wth     = (u16*)(ws + O_WTH);
    u16* wto     = (u16*)(ws + O_WTO);
    u16* wta     = (u16*)(ws + O_WTA);
    u16* wtb     = (u16*)(ws + O_WTB);
    // aliases (dead-buffer reuse)
    u16* ainput  = (u16*)(ws + O_NEI);                     // 54.5MB <= 67MB
    u16* atomh   = (u16*)(ws + O_FBP);                     // 33.5MB <= 42MB
    u16* hW      = (u16*)(ws + O_BINPUT);                  // 33.5MB
    u16* zbuf    = (u16*)(ws + O_BINPUT + 33554432);       // 33.5MB
    u16* atth    = (u16*)(ws + O_MESSAGE);                 // 33.5MB

    // prep
    prep_fbonds<<<81920, 256, 0, stream>>>(fbonds, fbp);
    prep_wt<<<160, 256, 0, stream>>>(W_i, wti, 157, KPAD_I);
    prep_wt<<<256, 256, 0, stream>>>(W_h, wth, 256, 256);
    prep_wo<<<416, 256, 0, stream>>>(W_o_w, wto);
    prep_wt<<<256, 256, 0, stream>>>(W_a, wta, 256, 256);
    prep_wt<<<256, 256, 0, stream>>>(W_b_w, wtb, 256, 256);

    dim3 gE(E_BONDS / 128, 2);
    dim3 gA(N_ATOMS_C / 128, 2);

    // binput = fbonds @ W_i ; message = relu(binput)
    gemm_bt<1><<<gE, 256, 0, stream>>>(fbp, wti, message, binput, nullptr, nullptr, KPAD_I);

    // 3 message-passing iterations
    for (int it = 0; it < 3; ++it) {
        bond_attn<<<E_BONDS / 4, 256, 0, stream>>>(message, bgraph, W_ma1, nei);
        gemm_bt<2><<<gE, 256, 0, stream>>>(nei, wth, message, nullptr, binput, nullptr, 256);
    }

    // atom stage
    atom_agg<<<N_ATOMS_C / 4, 256, 0, stream>>>(message, agraph, fatoms, ainput);
    gemm_bt<3><<<gA, 256, 0, stream>>>(ainput, wto, atomh, nullptr, nullptr, W_o_b, KPAD_O);

    // molecule attention
    gemm_bt<0><<<gA, 256, 0, stream>>>(atomh, wta, hW, nullptr, nullptr, nullptr, 256);
    mol_attn<<<N_MOLS, 256, 0, stream>>>(atomh, hW, zbuf);
    gemm_bt<3><<<gA, 256, 0, stream>>>(zbuf, wtb, atth, nullptr, nullptr, W_b_b, 256);

    final_reduce<<<N_MOLS, 256, 0, stream>>>(atomh, atth, out);
}